// Round 10
// baseline (252.202 us; speedup 1.0000x reference)
//
#include <hip/hip_runtime.h>
#include <hip/hip_bf16.h>
#include <math.h>

#define NB 2
#define NS 2048
#define ND 1024
#define NH 16
#define DH 64
#define MROWS (NB*NS)     // 4096
#define NCOLS (NH*DH)     // 1024

typedef __attribute__((ext_vector_type(8))) short bf16x8;
typedef __attribute__((ext_vector_type(4))) float f32x4;
typedef __attribute__((ext_vector_type(16))) float f32x16;
typedef __attribute__((ext_vector_type(8))) unsigned short ushort8t;
typedef unsigned short ushort;

extern "C" __device__ float __ocml_native_exp2_f32(float);
#define EXP2F(x) __ocml_native_exp2_f32(x)
#define LOG2E 1.44269504088896f

// HW bf16 convert (v_cvt_pk_bf16_f32 on gfx950)
static __device__ __forceinline__ ushort f2bf(float f) {
    union { __hip_bfloat16 b; ushort u; } cv;
    cv.b = __hip_bfloat16(f);
    return cv.u;
}

static __device__ __forceinline__ float bf2f(ushort u) {
    union { unsigned u; float f; } cv;
    cv.u = ((unsigned)u) << 16;
    return cv.f;
}

// packed pair convert: low16 = bf16(a), high16 = bf16(b)
static __device__ __forceinline__ unsigned cvtpk(float a, float b) {
    unsigned r;
    asm("v_cvt_pk_bf16_f32 %0, %1, %2" : "=v"(r) : "v"(a), "v"(b));
    return r;
}

static __device__ __forceinline__ float fmax3(float a, float b, float c) {
    return fmaxf(fmaxf(a, b), c);   // clang fuses to v_max3_f32
}

static __device__ __forceinline__ void gld_lds16(const void* g, void* l) {
    __builtin_amdgcn_global_load_lds(
        (const __attribute__((address_space(1))) void*)g,
        (__attribute__((address_space(3))) void*)l, 16, 0, 0);
}

// ---------------- merged prep kernel ----------------
// blocks [0,2048): X fp32->bf16 ; [2048,2816): Wq/Wk/Wv repack ; [2816,3072): Wo repack
__global__ __launch_bounds__(256) void prep_kernel(
    const float* __restrict__ q, const float* __restrict__ k,
    const float* __restrict__ v, ushort* __restrict__ X_bf,
    const float* __restrict__ Wq, const float* __restrict__ Wk,
    const float* __restrict__ Wv, ushort* __restrict__ WT_bf,
    const float* __restrict__ Wo, ushort* __restrict__ WoT_bf)
{
    const int bx = blockIdx.x;
    const int t = threadIdx.x;
    __shared__ float tile[64][65];

    if (bx < 2048) {
        const size_t n1 = (size_t)MROWS * ND;
        const size_t off = ((size_t)bx * 256 + t) * 8;
        const float* srcs[3] = {q, k, v};
        #pragma unroll
        for (int p = 0; p < 3; ++p) {
            float4 a = *(const float4*)(srcs[p] + off);
            float4 b = *(const float4*)(srcs[p] + off + 4);
            ushort8t w;
            w[0]=f2bf(a.x); w[1]=f2bf(a.y); w[2]=f2bf(a.z); w[3]=f2bf(a.w);
            w[4]=f2bf(b.x); w[5]=f2bf(b.y); w[6]=f2bf(b.z); w[7]=f2bf(b.w);
            *(ushort8t*)(X_bf + (size_t)p * n1 + off) = w;
        }
    } else if (bx < 2816) {
        const int i2 = bx - 2048;
        const int p = i2 >> 8;
        const int r = i2 & 255;
        const int h = r >> 4, d0 = (r & 15) * 64;
        const float* W = (p == 0) ? Wq : (p == 1) ? Wk : Wv;
        {
            const int i = t >> 2, e0 = (t & 3) * 16;
            const float* src = W + ((size_t)h * ND + d0 + i) * DH + e0;
            #pragma unroll
            for (int u = 0; u < 4; ++u) {
                float4 v4 = ((const float4*)src)[u];
                tile[i][e0 + u*4 + 0] = v4.x; tile[i][e0 + u*4 + 1] = v4.y;
                tile[i][e0 + u*4 + 2] = v4.z; tile[i][e0 + u*4 + 3] = v4.w;
            }
        }
        __syncthreads();
        {
            const int e = t >> 2, dc = (t & 3) * 16;
            ushort* dst = WT_bf + ((size_t)p * NCOLS + h * 64 + e) * ND + d0 + dc;
            ushort8t w0, w1;
            #pragma unroll
            for (int u = 0; u < 8; ++u) { w0[u] = f2bf(tile[dc+u][e]); w1[u] = f2bf(tile[dc+8+u][e]); }
            *(ushort8t*)dst = w0;
            *(ushort8t*)(dst + 8) = w1;
        }
    } else {
        const int i3 = bx - 2816;
        const int f0 = (i3 & 15) * 64, c0 = (i3 >> 4) * 64;
        {
            const int i = t >> 2, j0 = (t & 3) * 16;
            const float* src = Wo + (size_t)(f0 + i) * ND + c0 + j0;
            #pragma unroll
            for (int u = 0; u < 4; ++u) {
                float4 v4 = ((const float4*)src)[u];
                tile[i][j0 + u*4 + 0] = v4.x; tile[i][j0 + u*4 + 1] = v4.y;
                tile[i][j0 + u*4 + 2] = v4.z; tile[i][j0 + u*4 + 3] = v4.w;
            }
        }
        __syncthreads();
        {
            const int cl = t >> 2, fc = (t & 3) * 16;
            ushort* dst = WoT_bf + (size_t)(c0 + cl) * ND + f0 + fc;
            ushort8t w0, w1;
            #pragma unroll
            for (int u = 0; u < 8; ++u) { w0[u] = f2bf(tile[fc+u][cl]); w1[u] = f2bf(tile[fc+8+u][cl]); }
            *(ushort8t*)dst = w0;
            *(ushort8t*)(dst + 8) = w1;
        }
    }
}

// ---------------- Kernel: QKV projection GEMM, bf16 MFMA ----------------
// p=0: Q (scaled by 0.125*log2e) -> [bh][s][64]  (LDS-bounce coalesced epilogue)
// p=1: K -> [bh][s][64]                           (LDS-bounce coalesced epilogue)
// p=2: V -> V^T [bh][e][S] directly               (packed uint2, 4 consecutive s)
__global__ __launch_bounds__(256) void gemm_qkv(
    const ushort* __restrict__ X_bf, const ushort* __restrict__ WT_bf,
    const float* __restrict__ bq, const float* __restrict__ bk,
    const float* __restrict__ bv, ushort* __restrict__ qkv_bf,
    ushort* __restrict__ vT_bf)
{
    const int p = blockIdx.z;
    const float* bias = (p == 0) ? bq : (p == 1) ? bk : bv;
    const float scale = (p == 0) ? 0.125f * LOG2E : 1.0f;
    const int m0 = blockIdx.x * 128, n0 = blockIdx.y * 128;
    const int t = threadIdx.x, wid = t >> 6, lane = t & 63;
    const int wr = wid >> 1, wc = wid & 1;
    const int c = lane & 15, g = lane >> 4;

    __shared__ ushort ldsAB[2 * 128 * 64];
    ushort* ldsA = ldsAB;
    ushort* ldsB = ldsAB + 128 * 64;

    const ushort* Ag = X_bf + (size_t)p * MROWS * ND + (size_t)m0 * ND;
    const ushort* Bg = WT_bf + (size_t)p * NCOLS * ND + (size_t)n0 * ND;

    f32x4 acc[4][4];
    #pragma unroll
    for (int m = 0; m < 4; ++m)
        #pragma unroll
        for (int n = 0; n < 4; ++n)
            acc[m][n] = (f32x4){0.f, 0.f, 0.f, 0.f};

    for (int k0 = 0; k0 < ND; k0 += 64) {
        __syncthreads();
        #pragma unroll
        for (int call = 0; call < 4; ++call) {
            const int ch = wid * 256 + call * 64 + lane;
            const int row = ch >> 3, c16 = ch & 7;
            gld_lds16(Ag + (size_t)row * ND + k0 + c16 * 8, ldsA + (size_t)ch * 8);
            gld_lds16(Bg + (size_t)row * ND + k0 + c16 * 8, ldsB + (size_t)ch * 8);
        }
        __syncthreads();
        #pragma unroll
        for (int kc = 0; kc < 2; ++kc) {
            bf16x8 af[4], bfr[4];
            #pragma unroll
            for (int m = 0; m < 4; ++m)
                af[m] = *(const bf16x8*)(ldsA + (wr*64 + m*16 + c) * 64 + kc*32 + g*8);
            #pragma unroll
            for (int n = 0; n < 4; ++n)
                bfr[n] = *(const bf16x8*)(ldsB + (wc*64 + n*16 + c) * 64 + kc*32 + g*8);
            #pragma unroll
            for (int m = 0; m < 4; ++m)
                #pragma unroll
                for (int n = 0; n < 4; ++n)
                    acc[m][n] = __builtin_amdgcn_mfma_f32_16x16x32_bf16(af[m], bfr[n], acc[m][n], 0, 0, 0);
        }
    }

    if (p == 2) {
        #pragma unroll
        for (int m = 0; m < 4; ++m) {
            const int s0b = m0 + wr*64 + m*16 + g*4;
            const int b = s0b >> 11, sl = s0b & (NS - 1);
            #pragma unroll
            for (int n = 0; n < 4; ++n) {
                const int gc = n0 + wc*64 + n*16 + c;
                const int h = gc >> 6, e = gc & 63;
                const float bv_ = bias[gc];
                uint2 wv;
                wv.x = cvtpk(acc[m][n][0] + bv_, acc[m][n][1] + bv_);
                wv.y = cvtpk(acc[m][n][2] + bv_, acc[m][n][3] + bv_);
                *(uint2*)(vT_bf + ((size_t)(b * NH + h) * DH + e) * NS + sl) = wv;
            }
        }
    } else {
        __syncthreads();
        ushort* ldsC = ldsAB;
        #pragma unroll
        for (int m = 0; m < 4; ++m)
            #pragma unroll
            for (int n = 0; n < 4; ++n) {
                const int col = wc*64 + n*16 + c;
                const float bv_ = bias[n0 + col];
                #pragma unroll
                for (int j = 0; j < 4; ++j) {
                    const int row = wr*64 + m*16 + g*4 + j;
                    ldsC[row * 128 + col] = f2bf((acc[m][n][j] + bv_) * scale);
                }
            }
        __syncthreads();
        ushort* dstbase = qkv_bf + (size_t)p * ((size_t)NB * NH * NS * DH);
        #pragma unroll
        for (int rr = 0; rr < 8; ++rr) {
            const int idx = rr * 256 + t;
            const int row = idx >> 4;
            const int col0 = (idx & 15) * 8;
            const int gc = n0 + col0;
            const int h = gc >> 6, e0 = gc & 63;
            const int gr = m0 + row;
            const int b = gr >> 11, s = gr & (NS - 1);
            ushort8t w = *(ushort8t*)(ldsC + row * 128 + col0);
            *(ushort8t*)(dstbase + (((size_t)b * NH + h) * NS + s) * DH + e0) = w;
        }
    }
}

// ---------------- Kernel: flash attention, split-KV (2 halves), swapped 32x32 MFMA ----
// grid: 1024 1D blocks (XCD-mapped), block: 256 (4 waves, 32 q-rows each).
// Each block does 1024 keys (half). Emits normalized O (bf16) + (m,l) per row.
__global__ __launch_bounds__(256) void attn_kernel(
    const ushort* __restrict__ q_bf, const ushort* __restrict__ k_bf,
    const ushort* __restrict__ vT_bf, ushort* __restrict__ po,
    float2* __restrict__ pml)
{
    __shared__ __attribute__((aligned(16))) char smem[32768];
    const int t = threadIdx.x;
    const int wid = t >> 6, lane = t & 63;
    const int ql = lane & 31;
    const int hi = lane >> 5;

    // XCD-aware: 4 heads/XCD; per head 16 q-blocks x 2 KV-halves
    const int linear = blockIdx.x;          // 0..1023
    const int xcd = linear & 7;
    const int idx = linear >> 3;            // 0..127
    const int bh = xcd * 4 + (idx >> 5);
    const int sub = idx & 31;
    const int qx = sub >> 1;
    const int half = sub & 1;
    const int qrow0 = qx * 128 + wid * 32;
    const int hb = half * 1024;             // key-range base

    bf16x8 qf[4];
    {
        const char* qp = (const char*)(q_bf + ((size_t)bh * NS + qrow0 + ql) * DH);
        #pragma unroll
        for (int ds = 0; ds < 4; ++ds)
            qf[ds] = *(const bf16x8*)(qp + ds * 32 + hi * 16);
    }

    f32x16 o_acc[2];
    #pragma unroll
    for (int et = 0; et < 2; ++et)
        #pragma unroll
        for (int i = 0; i < 16; ++i)
            o_acc[et][i] = 0.f;
    float m = -INFINITY, lsum = 0.f;

    const char* kg = (const char*)(k_bf + (size_t)bh * NS * DH);
    const char* vg = (const char*)(vT_bf + (size_t)bh * DH * NS);

    const int ch0 = t * 2;
    const int row0 = ch0 >> 3, c16a = ch0 & 7;
    const int c16b = c16a + 1;
    const int swz0 = (c16a * 16) ^ ((row0 & 7) << 4);
    const int swz1 = (c16b * 16) ^ ((row0 & 7) << 4);

    ushort8t kr0, kr1, vr0, vr1;

    #define ATTN_LOAD(JT) do { \
        kr0 = *(const ushort8t*)(kg + (size_t)((JT) + row0) * 128 + c16a * 16); \
        kr1 = *(const ushort8t*)(kg + (size_t)((JT) + row0) * 128 + c16b * 16); \
        vr0 = *(const ushort8t*)(vg + (size_t)row0 * (NS*2) + (size_t)((JT) + c16a*8) * 2); \
        vr1 = *(const ushort8t*)(vg + (size_t)row0 * (NS*2) + (size_t)((JT) + c16b*8) * 2); \
    } while (0)

    #define ATTN_STORE(BUF) do { \
        char* Kd = smem + (BUF) * 8192; \
        char* Vd = smem + 16384 + (BUF) * 8192; \
        *(ushort8t*)(Kd + row0 * 128 + swz0) = kr0; \
        *(ushort8t*)(Kd + row0 * 128 + swz1) = kr1; \
        *(ushort8t*)(Vd + row0 * 128 + swz0) = vr0; \
        *(ushort8t*)(Vd + row0 * 128 + swz1) = vr1; \
    } while (0)

    ATTN_LOAD(hb);
    ATTN_STORE(0);
    __syncthreads();
    int cur = 0;

    for (int jt = hb; jt < hb + 1024; jt += 64) {
        ATTN_LOAD(hb + ((jt - hb + 64) & 1023));

        const char* Ks  = smem + cur * 8192;
        const char* VTs = smem + 16384 + cur * 8192;

        f32x16 s_acc[2];
        #pragma unroll
        for (int kt = 0; kt < 2; ++kt)
            #pragma unroll
            for (int i = 0; i < 16; ++i)
                s_acc[kt][i] = 0.f;
        __builtin_amdgcn_s_setprio(1);
        #pragma unroll
        for (int ds = 0; ds < 4; ++ds) {
            #pragma unroll
            for (int kt = 0; kt < 2; ++kt) {
                const int key = kt * 32 + ql;
                bf16x8 kf = *(const bf16x8*)(Ks + key * 128 + ((ds*32 + hi*16) ^ ((key & 7) << 4)));
                s_acc[kt] = __builtin_amdgcn_mfma_f32_32x32x16_bf16(kf, qf[ds], s_acc[kt], 0, 0, 0);
            }
        }
        __builtin_amdgcn_s_setprio(0);

        // lane-local online softmax (exp2 domain, defer-max thr 11.5), v_max3 tree
        float tm = fmaxf(s_acc[0][0], s_acc[0][1]);
        #pragma unroll
        for (int i = 2; i < 16; i += 2) tm = fmax3(tm, s_acc[0][i], s_acc[0][i+1]);
        #pragma unroll
        for (int i = 0; i < 16; i += 2) tm = fmax3(tm, s_acc[1][i], s_acc[1][i+1]);
        if (!__all(tm <= m + 11.5f)) {
            const float tm2 = fmaxf(tm, __shfl_xor(tm, 32));
            const float mnew = fmaxf(m, tm2);
            const float sc = EXP2F(m - mnew);
            lsum *= sc;
            #pragma unroll
            for (int et = 0; et < 2; ++et)
                #pragma unroll
                for (int i = 0; i < 16; ++i)
                    o_acc[et][i] *= sc;
            m = mnew;
        }

        float rs = 0.f;
        #pragma unroll
        for (int kt = 0; kt < 2; ++kt) {
            float pe[16];
            #pragma unroll
            for (int i = 0; i < 16; ++i) {
                pe[i] = EXP2F(s_acc[kt][i] - m);
                rs += pe[i];
            }
            unsigned a0 = cvtpk(pe[0],  pe[1]);
            unsigned a1 = cvtpk(pe[2],  pe[3]);
            unsigned b0 = cvtpk(pe[4],  pe[5]);
            unsigned b1 = cvtpk(pe[6],  pe[7]);
            asm volatile("v_permlane32_swap_b32 %0, %1" : "+v"(a0), "+v"(b0));
            asm volatile("v_permlane32_swap_b32 %0, %1" : "+v"(a1), "+v"(b1));
            unsigned c0 = cvtpk(pe[8],  pe[9]);
            unsigned c1 = cvtpk(pe[10], pe[11]);
            unsigned d0 = cvtpk(pe[12], pe[13]);
            unsigned d1 = cvtpk(pe[14], pe[15]);
            asm volatile("v_permlane32_swap_b32 %0, %1" : "+v"(c0), "+v"(d0));
            asm volatile("v_permlane32_swap_b32 %0, %1" : "+v"(c1), "+v"(d1));
            union { bf16x8 v; unsigned u[4]; } B0, B1;
            B0.u[0] = a0; B0.u[1] = a1; B0.u[2] = b0; B0.u[3] = b1;
            B1.u[0] = c0; B1.u[1] = c1; B1.u[2] = d0; B1.u[3] = d1;

            __builtin_amdgcn_s_setprio(1);
            #pragma unroll
            for (int et = 0; et < 2; ++et) {
                const int e = et * 32 + ql;
                bf16x8 vf0 = *(const bf16x8*)(VTs + e * 128 + (((2*kt)   * 32 + hi*16) ^ ((e & 7) << 4)));
                o_acc[et] = __builtin_amdgcn_mfma_f32_32x32x16_bf16(vf0, B0.v, o_acc[et], 0, 0, 0);
                bf16x8 vf1 = *(const bf16x8*)(VTs + e * 128 + (((2*kt+1) * 32 + hi*16) ^ ((e & 7) << 4)));
                o_acc[et] = __builtin_amdgcn_mfma_f32_32x32x16_bf16(vf1, B1.v, o_acc[et], 0, 0, 0);
            }
            __builtin_amdgcn_s_setprio(0);
        }
        lsum += rs;

        ATTN_STORE(cur ^ 1);
        __syncthreads();
        cur ^= 1;
    }

    lsum += __shfl_xor(lsum, 32);
    const float inv = 1.0f / lsum;

    // partial row index: (half*32 + bh)*NS + s
    const int s = qrow0 + ql;
    const size_t prow = (size_t)(half * 32 + bh) * NS + s;
    ushort* op = po + prow * DH;
    #pragma unroll
    for (int et = 0; et < 2; ++et) {
        #pragma unroll
        for (int rgrp = 0; rgrp < 4; ++rgrp) {
            uint2 wv;
            wv.x = cvtpk(o_acc[et][rgrp*4+0] * inv, o_acc[et][rgrp*4+1] * inv);
            wv.y = cvtpk(o_acc[et][rgrp*4+2] * inv, o_acc[et][rgrp*4+3] * inv);
            *(uint2*)(op + et*32 + rgrp*8 + hi*4) = wv;
        }
    }
    if (hi == 0) pml[prow] = make_float2(m, lsum);
    #undef ATTN_LOAD
    #undef ATTN_STORE
}

// ---------------- Kernel: merge split-KV partials -> cat layout ----------------
// grid: 256 blocks x 256 threads; thread = one (bh,s) row (64 e values).
__global__ __launch_bounds__(256) void merge_kernel(
    const ushort* __restrict__ po, const float2* __restrict__ pml,
    ushort* __restrict__ cat_bf)
{
    const int row = blockIdx.x * 256 + threadIdx.x;   // bh*NS + s
    const int bh = row >> 11, s = row & (NS - 1);
    const int b = bh >> 4, h = bh & 15;

    const float2 ml1 = pml[row];
    const float2 ml2 = pml[(size_t)32 * NS + row];
    const float M = fmaxf(ml1.x, ml2.x);
    const float w1 = ml1.y * EXP2F(ml1.x - M);
    const float w2 = ml2.y * EXP2F(ml2.x - M);
    const float inv = 1.0f / (w1 + w2);
    const float a1 = w1 * inv, a2 = w2 * inv;

    const ushort* p1 = po + (size_t)row * DH;
    const ushort* p2 = po + ((size_t)32 * NS + row) * DH;
    ushort* dst = cat_bf + ((size_t)b * NS + s) * NCOLS + h * DH;

    #pragma unroll
    for (int u = 0; u < 8; ++u) {
        ushort8t r1 = *(const ushort8t*)(p1 + u * 8);
        ushort8t r2 = *(const ushort8t*)(p2 + u * 8);
        union { ushort8t v; unsigned u32[4]; } w;
        #pragma unroll
        for (int j = 0; j < 4; ++j) {
            const float lo = a1 * bf2f(r1[2*j])   + a2 * bf2f(r2[2*j]);
            const float hh2 = a1 * bf2f(r1[2*j+1]) + a2 * bf2f(r2[2*j+1]);
            w.u32[j] = cvtpk(lo, hh2);
        }
        *(ushort8t*)(dst + u * 8) = w.v;
    }
}

// ---------------- Kernel: output GEMM, bf16 MFMA, fp32 out ----------------
__global__ __launch_bounds__(256) void gemm_out(
    const ushort* __restrict__ cat_bf, const ushort* __restrict__ WoT_bf,
    const float* __restrict__ bo, float* __restrict__ out)
{
    const int m0 = blockIdx.x * 128, n0 = blockIdx.y * 128;
    const int t = threadIdx.x, wid = t >> 6, lane = t & 63;
    const int wr = wid >> 1, wc = wid & 1;
    const int c = lane & 15, g = lane >> 4;

    __shared__ ushort ldsA[128 * 64];
    __shared__ ushort ldsB[128 * 64];

    const ushort* Ag = cat_bf + (size_t)m0 * ND;
    const ushort* Bg = WoT_bf + (size_t)n0 * ND;

    f32x4 acc[4][4];
    #pragma unroll
    for (int m = 0; m < 4; ++m)
        #pragma unroll
        for (int n = 0; n < 4; ++n)
            acc[m][n] = (f32x4){0.f, 0.f, 0.f, 0.f};

    for (int k0 = 0; k0 < ND; k0 += 64) {
        __syncthreads();
        #pragma unroll
        for (int call = 0; call < 4; ++call) {
            const int ch = wid * 256 + call * 64 + lane;
            const int row = ch >> 3, c16 = ch & 7;
            gld_lds16(Ag + (size_t)row * ND + k0 + c16 * 8, ldsA + (size_t)ch * 8);
            gld_lds16(Bg + (size_t)row * ND + k0 + c16 * 8, ldsB + (size_t)ch * 8);
        }
        __syncthreads();
        #pragma unroll
        for (int kc = 0; kc < 2; ++kc) {
            bf16x8 af[4], bfr[4];
            #pragma unroll
            for (int m = 0; m < 4; ++m)
                af[m] = *(const bf16x8*)(ldsA + (wr*64 + m*16 + c) * 64 + kc*32 + g*8);
            #pragma unroll
            for (int n = 0; n < 4; ++n)
                bfr[n] = *(const bf16x8*)(ldsB + (wc*64 + n*16 + c) * 64 + kc*32 + g*8);
            #pragma unroll
            for (int m = 0; m < 4; ++m)
                #pragma unroll
                for (int n = 0; n < 4; ++n)
                    acc[m][n] = __builtin_amdgcn_mfma_f32_16x16x32_bf16(af[m], bfr[n], acc[m][n], 0, 0, 0);
        }
    }

    #pragma unroll
    for (int m = 0; m < 4; ++m) {
        const int gr0 = m0 + wr*64 + m*16 + g*4;
        #pragma unroll
        for (int n = 0; n < 4; ++n) {
            const int gc = n0 + wc*64 + n*16 + c;
            const float bv_ = bo[gc];
            #pragma unroll
            for (int j = 0; j < 4; ++j)
                out[(size_t)(gr0 + j) * ND + gc] = acc[m][n][j] + bv_;
        }
    }
}

extern "C" void kernel_launch(void* const* d_in, const int* in_sizes, int n_in,
                              void* d_out, int out_size, void* d_ws, size_t ws_size,
                              hipStream_t stream) {
    const float* query = (const float*)d_in[0];
    const float* key_  = (const float*)d_in[1];
    const float* value = (const float*)d_in[2];
    const float* Wq = (const float*)d_in[3];
    const float* bq = (const float*)d_in[4];
    const float* Wk = (const float*)d_in[5];
    const float* bk = (const float*)d_in[6];
    const float* Wv = (const float*)d_in[7];
    const float* bv = (const float*)d_in[8];
    const float* Wo = (const float*)d_in[9];
    const float* bo = (const float*)d_in[10];
    float* out = (float*)d_out;

    const size_t per = (size_t)NB * NH * NS * DH;   // 4.19M elements
    const size_t xsz = (size_t)MROWS * ND;          // 4.19M

    ushort* X_bf   = (ushort*)d_ws;                 // 3*xsz (dead after gemm_qkv)
    ushort* qkv_bf = X_bf + 3 * xsz;                // q | k | (v slot unused)
    ushort* vT_bf  = qkv_bf + 3 * per;              // per
    ushort* WT_bf  = vT_bf + per;                   // 3*1024*1024
    ushort* WoT_bf = WT_bf + (size_t)3 * ND * NCOLS;// 1024*1024
    // aliases over dead regions:
    ushort* cat_bf = X_bf;                          // per (first third of X)
    ushort* po     = X_bf + per;                    // 2*per (rest of X region)
    float2* pml    = (float2*)(qkv_bf + 2 * per);   // 2*32*NS float2 = 1 MB (v slot)

    prep_kernel<<<3072, 256, 0, stream>>>(query, key_, value, X_bf,
                                          Wq, Wk, Wv, WT_bf, Wo, WoT_bf);

    gemm_qkv<<<dim3(32, 8, 3), 256, 0, stream>>>(X_bf, WT_bf, bq, bk, bv, qkv_bf, vT_bf);

    attn_kernel<<<1024, 256, 0, stream>>>(qkv_bf, qkv_bf + per, vT_bf, po, pml);

    merge_kernel<<<256, 256, 0, stream>>>(po, pml, cat_bf);

    gemm_out<<<dim3(32, 8), 256, 0, stream>>>(cat_bf, WoT_bf, bo, out);
}

// Round 11
// 236.436 us; speedup vs baseline: 1.0667x; 1.0667x over previous
//
#include <hip/hip_runtime.h>
#include <hip/hip_bf16.h>
#include <math.h>

#define NB 2
#define NS 2048
#define ND 1024
#define NH 16
#define DH 64
#define MROWS (NB*NS)     // 4096
#define NCOLS (NH*DH)     // 1024

typedef __attribute__((ext_vector_type(8))) short bf16x8;
typedef __attribute__((ext_vector_type(4))) float f32x4;
typedef __attribute__((ext_vector_type(16))) float f32x16;
typedef __attribute__((ext_vector_type(8))) unsigned short ushort8t;
typedef unsigned short ushort;

extern "C" __device__ float __ocml_native_exp2_f32(float);
#define EXP2F(x) __ocml_native_exp2_f32(x)
#define LOG2E 1.44269504088896f

// HW bf16 convert (v_cvt_pk_bf16_f32 on gfx950)
static __device__ __forceinline__ ushort f2bf(float f) {
    union { __hip_bfloat16 b; ushort u; } cv;
    cv.b = __hip_bfloat16(f);
    return cv.u;
}

// packed pair convert: low16 = bf16(a), high16 = bf16(b)
static __device__ __forceinline__ unsigned cvtpk(float a, float b) {
    unsigned r;
    asm("v_cvt_pk_bf16_f32 %0, %1, %2" : "=v"(r) : "v"(a), "v"(b));
    return r;
}

static __device__ __forceinline__ float fmax3(float a, float b, float c) {
    return fmaxf(fmaxf(a, b), c);   // clang fuses to v_max3_f32
}

static __device__ __forceinline__ void gld_lds16(const void* g, void* l) {
    __builtin_amdgcn_global_load_lds(
        (const __attribute__((address_space(1))) void*)g,
        (__attribute__((address_space(3))) void*)l, 16, 0, 0);
}

// ---------------- merged prep kernel ----------------
// blocks [0,2048): X fp32->bf16 ; [2048,2816): Wq/Wk/Wv repack ; [2816,3072): Wo repack
__global__ __launch_bounds__(256) void prep_kernel(
    const float* __restrict__ q, const float* __restrict__ k,
    const float* __restrict__ v, ushort* __restrict__ X_bf,
    const float* __restrict__ Wq, const float* __restrict__ Wk,
    const float* __restrict__ Wv, ushort* __restrict__ WT_bf,
    const float* __restrict__ Wo, ushort* __restrict__ WoT_bf)
{
    const int bx = blockIdx.x;
    const int t = threadIdx.x;
    __shared__ float tile[64][65];

    if (bx < 2048) {
        const size_t n1 = (size_t)MROWS * ND;
        const size_t off = ((size_t)bx * 256 + t) * 8;
        const float* srcs[3] = {q, k, v};
        #pragma unroll
        for (int p = 0; p < 3; ++p) {
            float4 a = *(const float4*)(srcs[p] + off);
            float4 b = *(const float4*)(srcs[p] + off + 4);
            ushort8t w;
            w[0]=f2bf(a.x); w[1]=f2bf(a.y); w[2]=f2bf(a.z); w[3]=f2bf(a.w);
            w[4]=f2bf(b.x); w[5]=f2bf(b.y); w[6]=f2bf(b.z); w[7]=f2bf(b.w);
            *(ushort8t*)(X_bf + (size_t)p * n1 + off) = w;
        }
    } else if (bx < 2816) {
        const int i2 = bx - 2048;
        const int p = i2 >> 8;
        const int r = i2 & 255;
        const int h = r >> 4, d0 = (r & 15) * 64;
        const float* W = (p == 0) ? Wq : (p == 1) ? Wk : Wv;
        {
            const int i = t >> 2, e0 = (t & 3) * 16;
            const float* src = W + ((size_t)h * ND + d0 + i) * DH + e0;
            #pragma unroll
            for (int u = 0; u < 4; ++u) {
                float4 v4 = ((const float4*)src)[u];
                tile[i][e0 + u*4 + 0] = v4.x; tile[i][e0 + u*4 + 1] = v4.y;
                tile[i][e0 + u*4 + 2] = v4.z; tile[i][e0 + u*4 + 3] = v4.w;
            }
        }
        __syncthreads();
        {
            const int e = t >> 2, dc = (t & 3) * 16;
            ushort* dst = WT_bf + ((size_t)p * NCOLS + h * 64 + e) * ND + d0 + dc;
            ushort8t w0, w1;
            #pragma unroll
            for (int u = 0; u < 8; ++u) { w0[u] = f2bf(tile[dc+u][e]); w1[u] = f2bf(tile[dc+8+u][e]); }
            *(ushort8t*)dst = w0;
            *(ushort8t*)(dst + 8) = w1;
        }
    } else {
        const int i3 = bx - 2816;
        const int f0 = (i3 & 15) * 64, c0 = (i3 >> 4) * 64;
        {
            const int i = t >> 2, j0 = (t & 3) * 16;
            const float* src = Wo + (size_t)(f0 + i) * ND + c0 + j0;
            #pragma unroll
            for (int u = 0; u < 4; ++u) {
                float4 v4 = ((const float4*)src)[u];
                tile[i][j0 + u*4 + 0] = v4.x; tile[i][j0 + u*4 + 1] = v4.y;
                tile[i][j0 + u*4 + 2] = v4.z; tile[i][j0 + u*4 + 3] = v4.w;
            }
        }
        __syncthreads();
        {
            const int cl = t >> 2, fc = (t & 3) * 16;
            ushort* dst = WoT_bf + (size_t)(c0 + cl) * ND + f0 + fc;
            ushort8t w0, w1;
            #pragma unroll
            for (int u = 0; u < 8; ++u) { w0[u] = f2bf(tile[fc+u][cl]); w1[u] = f2bf(tile[fc+8+u][cl]); }
            *(ushort8t*)dst = w0;
            *(ushort8t*)(dst + 8) = w1;
        }
    }
}

// ---------------- Kernel: QKV projection GEMM, bf16 MFMA ----------------
// p=0: Q (scaled by 0.125*log2e) -> [bh][s][64]  (LDS-bounce coalesced epilogue)
// p=1: K -> [bh][s][64]                           (LDS-bounce coalesced epilogue)
// p=2: V -> V^T [bh][e][S] directly               (packed uint2, 4 consecutive s)
__global__ __launch_bounds__(256) void gemm_qkv(
    const ushort* __restrict__ X_bf, const ushort* __restrict__ WT_bf,
    const float* __restrict__ bq, const float* __restrict__ bk,
    const float* __restrict__ bv, ushort* __restrict__ qkv_bf,
    ushort* __restrict__ vT_bf)
{
    const int p = blockIdx.z;
    const float* bias = (p == 0) ? bq : (p == 1) ? bk : bv;
    const float scale = (p == 0) ? 0.125f * LOG2E : 1.0f;
    const int m0 = blockIdx.x * 128, n0 = blockIdx.y * 128;
    const int t = threadIdx.x, wid = t >> 6, lane = t & 63;
    const int wr = wid >> 1, wc = wid & 1;
    const int c = lane & 15, g = lane >> 4;

    __shared__ ushort ldsAB[2 * 128 * 64];
    ushort* ldsA = ldsAB;
    ushort* ldsB = ldsAB + 128 * 64;

    const ushort* Ag = X_bf + (size_t)p * MROWS * ND + (size_t)m0 * ND;
    const ushort* Bg = WT_bf + (size_t)p * NCOLS * ND + (size_t)n0 * ND;

    f32x4 acc[4][4];
    #pragma unroll
    for (int m = 0; m < 4; ++m)
        #pragma unroll
        for (int n = 0; n < 4; ++n)
            acc[m][n] = (f32x4){0.f, 0.f, 0.f, 0.f};

    for (int k0 = 0; k0 < ND; k0 += 64) {
        __syncthreads();
        #pragma unroll
        for (int call = 0; call < 4; ++call) {
            const int ch = wid * 256 + call * 64 + lane;
            const int row = ch >> 3, c16 = ch & 7;
            gld_lds16(Ag + (size_t)row * ND + k0 + c16 * 8, ldsA + (size_t)ch * 8);
            gld_lds16(Bg + (size_t)row * ND + k0 + c16 * 8, ldsB + (size_t)ch * 8);
        }
        __syncthreads();
        #pragma unroll
        for (int kc = 0; kc < 2; ++kc) {
            bf16x8 af[4], bfr[4];
            #pragma unroll
            for (int m = 0; m < 4; ++m)
                af[m] = *(const bf16x8*)(ldsA + (wr*64 + m*16 + c) * 64 + kc*32 + g*8);
            #pragma unroll
            for (int n = 0; n < 4; ++n)
                bfr[n] = *(const bf16x8*)(ldsB + (wc*64 + n*16 + c) * 64 + kc*32 + g*8);
            #pragma unroll
            for (int m = 0; m < 4; ++m)
                #pragma unroll
                for (int n = 0; n < 4; ++n)
                    acc[m][n] = __builtin_amdgcn_mfma_f32_16x16x32_bf16(af[m], bfr[n], acc[m][n], 0, 0, 0);
        }
    }

    if (p == 2) {
        #pragma unroll
        for (int m = 0; m < 4; ++m) {
            const int s0b = m0 + wr*64 + m*16 + g*4;
            const int b = s0b >> 11, sl = s0b & (NS - 1);
            #pragma unroll
            for (int n = 0; n < 4; ++n) {
                const int gc = n0 + wc*64 + n*16 + c;
                const int h = gc >> 6, e = gc & 63;
                const float bv_ = bias[gc];
                uint2 wv;
                wv.x = cvtpk(acc[m][n][0] + bv_, acc[m][n][1] + bv_);
                wv.y = cvtpk(acc[m][n][2] + bv_, acc[m][n][3] + bv_);
                *(uint2*)(vT_bf + ((size_t)(b * NH + h) * DH + e) * NS + sl) = wv;
            }
        }
    } else {
        __syncthreads();
        ushort* ldsC = ldsAB;
        #pragma unroll
        for (int m = 0; m < 4; ++m)
            #pragma unroll
            for (int n = 0; n < 4; ++n) {
                const int col = wc*64 + n*16 + c;
                const float bv_ = bias[n0 + col];
                #pragma unroll
                for (int j = 0; j < 4; ++j) {
                    const int row = wr*64 + m*16 + g*4 + j;
                    ldsC[row * 128 + col] = f2bf((acc[m][n][j] + bv_) * scale);
                }
            }
        __syncthreads();
        ushort* dstbase = qkv_bf + (size_t)p * ((size_t)NB * NH * NS * DH);
        #pragma unroll
        for (int rr = 0; rr < 8; ++rr) {
            const int idx = rr * 256 + t;
            const int row = idx >> 4;
            const int col0 = (idx & 15) * 8;
            const int gc = n0 + col0;
            const int h = gc >> 6, e0 = gc & 63;
            const int gr = m0 + row;
            const int b = gr >> 11, s = gr & (NS - 1);
            ushort8t w = *(ushort8t*)(ldsC + row * 128 + col0);
            *(ushort8t*)(dstbase + (((size_t)b * NH + h) * NS + s) * DH + e0) = w;
        }
    }
}

// ---------------- Kernel: flash attention, swapped 32x32 MFMA, in-register softmax ----
// grid: 512 1D blocks (XCD-mapped), block: 256 (4 waves, 32 q-rows each).
__global__ __launch_bounds__(256) void attn_kernel(
    const ushort* __restrict__ q_bf, const ushort* __restrict__ k_bf,
    const ushort* __restrict__ vT_bf, ushort* __restrict__ cat_bf)
{
    __shared__ __attribute__((aligned(16))) char smem[32768];
    const int t = threadIdx.x;
    const int wid = t >> 6, lane = t & 63;
    const int ql = lane & 31;
    const int hi = lane >> 5;

    const int linear = blockIdx.x;
    const int xcd = linear & 7;
    const int idx = linear >> 3;
    const int bh = xcd * 4 + (idx >> 4);
    const int qx = idx & 15;
    const int qrow0 = qx * 128 + wid * 32;

    bf16x8 qf[4];
    {
        const char* qp = (const char*)(q_bf + ((size_t)bh * NS + qrow0 + ql) * DH);
        #pragma unroll
        for (int ds = 0; ds < 4; ++ds)
            qf[ds] = *(const bf16x8*)(qp + ds * 32 + hi * 16);
    }

    f32x16 o_acc[2];
    #pragma unroll
    for (int et = 0; et < 2; ++et)
        #pragma unroll
        for (int i = 0; i < 16; ++i)
            o_acc[et][i] = 0.f;
    float m = -INFINITY, lsum = 0.f;

    const char* kg = (const char*)(k_bf + (size_t)bh * NS * DH);
    const char* vg = (const char*)(vT_bf + (size_t)bh * DH * NS);

    const int ch0 = t * 2;
    const int row0 = ch0 >> 3, c16a = ch0 & 7;
    const int c16b = c16a + 1;
    const int swz0 = (c16a * 16) ^ ((row0 & 7) << 4);
    const int swz1 = (c16b * 16) ^ ((row0 & 7) << 4);

    ushort8t kr0, kr1, vr0, vr1;

    #define ATTN_LOAD(JT) do { \
        kr0 = *(const ushort8t*)(kg + (size_t)((JT) + row0) * 128 + c16a * 16); \
        kr1 = *(const ushort8t*)(kg + (size_t)((JT) + row0) * 128 + c16b * 16); \
        vr0 = *(const ushort8t*)(vg + (size_t)row0 * (NS*2) + (size_t)((JT) + c16a*8) * 2); \
        vr1 = *(const ushort8t*)(vg + (size_t)row0 * (NS*2) + (size_t)((JT) + c16b*8) * 2); \
    } while (0)

    #define ATTN_STORE(BUF) do { \
        char* Kd = smem + (BUF) * 8192; \
        char* Vd = smem + 16384 + (BUF) * 8192; \
        *(ushort8t*)(Kd + row0 * 128 + swz0) = kr0; \
        *(ushort8t*)(Kd + row0 * 128 + swz1) = kr1; \
        *(ushort8t*)(Vd + row0 * 128 + swz0) = vr0; \
        *(ushort8t*)(Vd + row0 * 128 + swz1) = vr1; \
    } while (0)

    ATTN_LOAD(0);
    ATTN_STORE(0);
    __syncthreads();
    int cur = 0;

    for (int jt = 0; jt < NS; jt += 64) {
        ATTN_LOAD((jt + 64) & (NS - 1));

        const char* Ks  = smem + cur * 8192;
        const char* VTs = smem + 16384 + cur * 8192;

        f32x16 s_acc[2];
        #pragma unroll
        for (int kt = 0; kt < 2; ++kt)
            #pragma unroll
            for (int i = 0; i < 16; ++i)
                s_acc[kt][i] = 0.f;
        __builtin_amdgcn_s_setprio(1);
        #pragma unroll
        for (int ds = 0; ds < 4; ++ds) {
            #pragma unroll
            for (int kt = 0; kt < 2; ++kt) {
                const int key = kt * 32 + ql;
                bf16x8 kf = *(const bf16x8*)(Ks + key * 128 + ((ds*32 + hi*16) ^ ((key & 7) << 4)));
                s_acc[kt] = __builtin_amdgcn_mfma_f32_32x32x16_bf16(kf, qf[ds], s_acc[kt], 0, 0, 0);
            }
        }
        __builtin_amdgcn_s_setprio(0);

        // lane-local online softmax (exp2 domain, defer-max thr 11.5), v_max3 tree
        float tm = fmaxf(s_acc[0][0], s_acc[0][1]);
        #pragma unroll
        for (int i = 2; i < 16; i += 2) tm = fmax3(tm, s_acc[0][i], s_acc[0][i+1]);
        #pragma unroll
        for (int i = 0; i < 16; i += 2) tm = fmax3(tm, s_acc[1][i], s_acc[1][i+1]);
        if (!__all(tm <= m + 11.5f)) {
            const float tm2 = fmaxf(tm, __shfl_xor(tm, 32));
            const float mnew = fmaxf(m, tm2);
            const float sc = EXP2F(m - mnew);
            lsum *= sc;
            #pragma unroll
            for (int et = 0; et < 2; ++et)
                #pragma unroll
                for (int i = 0; i < 16; ++i)
                    o_acc[et][i] *= sc;
            m = mnew;
        }

        float rs = 0.f;
        #pragma unroll
        for (int kt = 0; kt < 2; ++kt) {
            float pe[16];
            #pragma unroll
            for (int i = 0; i < 16; ++i) {
                pe[i] = EXP2F(s_acc[kt][i] - m);
                rs += pe[i];
            }
            unsigned a0 = cvtpk(pe[0],  pe[1]);
            unsigned a1 = cvtpk(pe[2],  pe[3]);
            unsigned b0 = cvtpk(pe[4],  pe[5]);
            unsigned b1 = cvtpk(pe[6],  pe[7]);
            asm volatile("v_permlane32_swap_b32 %0, %1" : "+v"(a0), "+v"(b0));
            asm volatile("v_permlane32_swap_b32 %0, %1" : "+v"(a1), "+v"(b1));
            unsigned c0 = cvtpk(pe[8],  pe[9]);
            unsigned c1 = cvtpk(pe[10], pe[11]);
            unsigned d0 = cvtpk(pe[12], pe[13]);
            unsigned d1 = cvtpk(pe[14], pe[15]);
            asm volatile("v_permlane32_swap_b32 %0, %1" : "+v"(c0), "+v"(d0));
            asm volatile("v_permlane32_swap_b32 %0, %1" : "+v"(c1), "+v"(d1));
            union { bf16x8 v; unsigned u[4]; } B0, B1;
            B0.u[0] = a0; B0.u[1] = a1; B0.u[2] = b0; B0.u[3] = b1;
            B1.u[0] = c0; B1.u[1] = c1; B1.u[2] = d0; B1.u[3] = d1;

            __builtin_amdgcn_s_setprio(1);
            #pragma unroll
            for (int et = 0; et < 2; ++et) {
                const int e = et * 32 + ql;
                bf16x8 vf0 = *(const bf16x8*)(VTs + e * 128 + (((2*kt)   * 32 + hi*16) ^ ((e & 7) << 4)));
                o_acc[et] = __builtin_amdgcn_mfma_f32_32x32x16_bf16(vf0, B0.v, o_acc[et], 0, 0, 0);
                bf16x8 vf1 = *(const bf16x8*)(VTs + e * 128 + (((2*kt+1) * 32 + hi*16) ^ ((e & 7) << 4)));
                o_acc[et] = __builtin_amdgcn_mfma_f32_32x32x16_bf16(vf1, B1.v, o_acc[et], 0, 0, 0);
            }
            __builtin_amdgcn_s_setprio(0);
        }
        lsum += rs;

        ATTN_STORE(cur ^ 1);
        __syncthreads();
        cur ^= 1;
    }

    lsum += __shfl_xor(lsum, 32);
    const float inv = 1.0f / lsum;

    const int b = bh >> 4, hh = bh & 15;
    const int s = qrow0 + ql;
    ushort* op = cat_bf + ((size_t)b * NS + s) * NCOLS + hh * DH;
    #pragma unroll
    for (int et = 0; et < 2; ++et) {
        #pragma unroll
        for (int rgrp = 0; rgrp < 4; ++rgrp) {
            uint2 wv;
            wv.x = cvtpk(o_acc[et][rgrp*4+0] * inv, o_acc[et][rgrp*4+1] * inv);
            wv.y = cvtpk(o_acc[et][rgrp*4+2] * inv, o_acc[et][rgrp*4+3] * inv);
            *(uint2*)(op + et*32 + rgrp*8 + hi*4) = wv;
        }
    }
    #undef ATTN_LOAD
    #undef ATTN_STORE
}

// ---------------- Kernel: output GEMM, bf16 MFMA, fp32 out ----------------
// 64x128 tiles -> grid (64,8) = 512 blocks = 2 blocks/CU (was 1 -> latency-bound)
__global__ __launch_bounds__(256) void gemm_out(
    const ushort* __restrict__ cat_bf, const ushort* __restrict__ WoT_bf,
    const float* __restrict__ bo, float* __restrict__ out)
{
    const int m0 = blockIdx.x * 64, n0 = blockIdx.y * 128;
    const int t = threadIdx.x, wid = t >> 6, lane = t & 63;
    const int wc = wid;                 // wave covers 64 rows x 32 cols
    const int c = lane & 15, g = lane >> 4;

    __shared__ ushort ldsA[64 * 64];    // 8 KB
    __shared__ ushort ldsB[128 * 64];   // 16 KB

    const ushort* Ag = cat_bf + (size_t)m0 * ND;
    const ushort* Bg = WoT_bf + (size_t)n0 * ND;

    f32x4 acc[4][2];
    #pragma unroll
    for (int m = 0; m < 4; ++m)
        #pragma unroll
        for (int n = 0; n < 2; ++n)
            acc[m][n] = (f32x4){0.f, 0.f, 0.f, 0.f};

    for (int k0 = 0; k0 < ND; k0 += 64) {
        __syncthreads();
        #pragma unroll
        for (int u = 0; u < 2; ++u) {   // A: 512 16B-chunks, 2/thread
            const int ch = u * 256 + t;
            const int row = ch >> 3, c16 = ch & 7;
            gld_lds16(Ag + (size_t)row * ND + k0 + c16 * 8, ldsA + (size_t)ch * 8);
        }
        #pragma unroll
        for (int u = 0; u < 4; ++u) {   // B: 1024 16B-chunks, 4/thread
            const int ch = u * 256 + t;
            const int row = ch >> 3, c16 = ch & 7;
            gld_lds16(Bg + (size_t)row * ND + k0 + c16 * 8, ldsB + (size_t)ch * 8);
        }
        __syncthreads();
        #pragma unroll
        for (int kc = 0; kc < 2; ++kc) {
            bf16x8 af[4], bfr[2];
            #pragma unroll
            for (int m = 0; m < 4; ++m)
                af[m] = *(const bf16x8*)(ldsA + (m*16 + c) * 64 + kc*32 + g*8);
            #pragma unroll
            for (int n = 0; n < 2; ++n)
                bfr[n] = *(const bf16x8*)(ldsB + (wc*32 + n*16 + c) * 64 + kc*32 + g*8);
            #pragma unroll
            for (int m = 0; m < 4; ++m)
                #pragma unroll
                for (int n = 0; n < 2; ++n)
                    acc[m][n] = __builtin_amdgcn_mfma_f32_16x16x32_bf16(af[m], bfr[n], acc[m][n], 0, 0, 0);
        }
    }

    #pragma unroll
    for (int m = 0; m < 4; ++m) {
        const int gr0 = m0 + m*16 + g*4;
        #pragma unroll
        for (int n = 0; n < 2; ++n) {
            const int gc = n0 + wc*32 + n*16 + c;
            const float bv_ = bo[gc];
            #pragma unroll
            for (int j = 0; j < 4; ++j)
                out[(size_t)(gr0 + j) * ND + gc] = acc[m][n][j] + bv_;
        }
    }
}

extern "C" void kernel_launch(void* const* d_in, const int* in_sizes, int n_in,
                              void* d_out, int out_size, void* d_ws, size_t ws_size,
                              hipStream_t stream) {
    const float* query = (const float*)d_in[0];
    const float* key_  = (const float*)d_in[1];
    const float* value = (const float*)d_in[2];
    const float* Wq = (const float*)d_in[3];
    const float* bq = (const float*)d_in[4];
    const float* Wk = (const float*)d_in[5];
    const float* bk = (const float*)d_in[6];
    const float* Wv = (const float*)d_in[7];
    const float* bv = (const float*)d_in[8];
    const float* Wo = (const float*)d_in[9];
    const float* bo = (const float*)d_in[10];
    float* out = (float*)d_out;

    const size_t per = (size_t)NB * NH * NS * DH;   // 4.19M elements
    const size_t xsz = (size_t)MROWS * ND;          // 4.19M

    ushort* X_bf   = (ushort*)d_ws;                 // 3*xsz (dead after gemm_qkv)
    ushort* qkv_bf = X_bf + 3 * xsz;                // q | k | (v slot unused)
    ushort* vT_bf  = qkv_bf + 3 * per;              // per
    ushort* WT_bf  = vT_bf + per;                   // 3*1024*1024
    ushort* WoT_bf = WT_bf + (size_t)3 * ND * NCOLS;// 1024*1024
    ushort* cat_bf = X_bf;                          // alias: X dead after gemm_qkv

    prep_kernel<<<3072, 256, 0, stream>>>(query, key_, value, X_bf,
                                          Wq, Wk, Wv, WT_bf, Wo, WoT_bf);

    gemm_qkv<<<dim3(32, 8, 3), 256, 0, stream>>>(X_bf, WT_bf, bq, bk, bv, qkv_bf, vT_bf);

    attn_kernel<<<512, 256, 0, stream>>>(qkv_bf, qkv_bf + per, vT_bf, cat_bf);

    gemm_out<<<dim3(64, 8), 256, 0, stream>>>(cat_bf, WoT_bf, bo, out);
}